// Round 2
// baseline (189.928 us; speedup 1.0000x reference)
//
#include <hip/hip_runtime.h>
#include <hip/hip_bf16.h>

#define EMB 768
#define HEADS 12
#define DKV 64
#define BATCH 2
#define SEQ 2048
#define NTOK (BATCH*SEQ)   // 4096

typedef float f32x4 __attribute__((ext_vector_type(4)));
typedef unsigned short u16;
typedef u16 u16x8 __attribute__((ext_vector_type(8)));
typedef __bf16 bf16x8 __attribute__((ext_vector_type(8)));

__device__ __forceinline__ u16 f2bf(float f) {
  union { float f; unsigned u; } v; v.f = f;
  unsigned r = v.u + 0x7FFFu + ((v.u >> 16) & 1u);
  return (u16)(r >> 16);
}

__device__ __forceinline__ f32x4 mfma16(u16x8 a, u16x8 b, f32x4 c) {
  return __builtin_amdgcn_mfma_f32_16x16x32_bf16(
      __builtin_bit_cast(bf16x8, a), __builtin_bit_cast(bf16x8, b), c, 0, 0, 0);
}

// ---------------- cast fp32 -> bf16 (optionally scaled), vectorized ----------------
__global__ void cast_bf16_k(const float* __restrict__ src, u16* __restrict__ dst,
                            int n8, float scale) {
  int i = blockIdx.x * blockDim.x + threadIdx.x;
  int stride = gridDim.x * blockDim.x;
  for (; i < n8; i += stride) {
    float4 a = reinterpret_cast<const float4*>(src)[i*2];
    float4 b = reinterpret_cast<const float4*>(src)[i*2+1];
    u16x8 o;
    o[0]=f2bf(a.x*scale); o[1]=f2bf(a.y*scale); o[2]=f2bf(a.z*scale); o[3]=f2bf(a.w*scale);
    o[4]=f2bf(b.x*scale); o[5]=f2bf(b.y*scale); o[6]=f2bf(b.z*scale); o[7]=f2bf(b.w*scale);
    reinterpret_cast<u16x8*>(dst)[i] = o;
  }
}

// ---------------- GEMM: C[4096,768] = A[4096,768] @ B[768,768]^T + bias ----------------
// BM=64, BN=128, BK=64. 256 threads = 4 waves (2x2), each wave 32x64 out.
// LDS tiles XOR-swizzled: physical_slot = logical_slot ^ (row&7) (16B slots, 128B rows).
// MODE 0: out bf16 head-split [B][H][S][DKV] (+bias*bscale). MODE 1: out fp32 [M][EMB] (+bias).
template<int MODE>
__global__ __launch_bounds__(256) void gemm_bt_k(
    const u16* __restrict__ A, const u16* __restrict__ Bm,
    const float* __restrict__ bias, float bscale, void* __restrict__ outp)
{
  __shared__ __align__(16) u16 At[64*64];
  __shared__ __align__(16) u16 Bt[128*64];
  const int t = threadIdx.x;
  const int w = t >> 6, lane = t & 63, lg = lane >> 4, lr = lane & 15;
  const int wr = w >> 1, wc = w & 1;
  const int m0 = blockIdx.x * 64, n0 = blockIdx.y * 128;

  f32x4 acc[2][4] = {};

  for (int kb = 0; kb < EMB; kb += 64) {
    #pragma unroll
    for (int q = 0; q < 2; ++q) {
      int c = q*256 + t;
      int row = c >> 3, sl = c & 7;
      u16x8 v = *reinterpret_cast<const u16x8*>(A + (size_t)(m0+row)*EMB + kb + sl*8);
      *reinterpret_cast<u16x8*>(At + row*64 + ((sl ^ (row & 7))*8)) = v;
    }
    #pragma unroll
    for (int q = 0; q < 4; ++q) {
      int c = q*256 + t;
      int row = c >> 3, sl = c & 7;
      u16x8 v = *reinterpret_cast<const u16x8*>(Bm + (size_t)(n0+row)*EMB + kb + sl*8);
      *reinterpret_cast<u16x8*>(Bt + row*64 + ((sl ^ (row & 7))*8)) = v;
    }
    __syncthreads();

    u16x8 af[2][2], bfr[4][2];
    #pragma unroll
    for (int fm = 0; fm < 2; ++fm)
      #pragma unroll
      for (int kk = 0; kk < 2; ++kk) {
        int r = wr*32 + fm*16 + lr;
        int slot = (lg + 4*kk) ^ (r & 7);
        af[fm][kk] = *reinterpret_cast<const u16x8*>(At + r*64 + slot*8);
      }
    #pragma unroll
    for (int fn = 0; fn < 4; ++fn)
      #pragma unroll
      for (int kk = 0; kk < 2; ++kk) {
        int r = wc*64 + fn*16 + lr;
        int slot = (lg + 4*kk) ^ (r & 7);
        bfr[fn][kk] = *reinterpret_cast<const u16x8*>(Bt + r*64 + slot*8);
      }
    #pragma unroll
    for (int fm = 0; fm < 2; ++fm)
      #pragma unroll
      for (int fn = 0; fn < 4; ++fn)
        #pragma unroll
        for (int kk = 0; kk < 2; ++kk)
          acc[fm][fn] = mfma16(af[fm][kk], bfr[fn][kk], acc[fm][fn]);
    __syncthreads();
  }

  // epilogue: C layout col = lane&15, row = (lane>>4)*4 + j  [measured m89]
  #pragma unroll
  for (int fm = 0; fm < 2; ++fm)
    #pragma unroll
    for (int fn = 0; fn < 4; ++fn)
      #pragma unroll
      for (int j = 0; j < 4; ++j) {
        int m = m0 + wr*32 + fm*16 + lg*4 + j;
        int e = n0 + wc*64 + fn*16 + lr;
        float val = acc[fm][fn][j] + bias[e] * bscale;
        if (MODE == 0) {
          int bb = m >> 11, s = m & 2047, h = e >> 6, d = e & 63;
          reinterpret_cast<u16*>(outp)[(((size_t)(bb*HEADS + h))*SEQ + s)*DKV + d] = f2bf(val);
        } else {
          reinterpret_cast<float*>(outp)[(size_t)m*EMB + e] = val;
        }
      }
}

// ---------------- flash attention ----------------
// Q pre-scaled by 0.125*log2(e) (folded into Wq/bq) -> softmax in base-2 via exp2f.
// 4 waves x 16 q-rows, K-tiles of 64. All LDS write->read pairs cross __syncthreads().
__global__ __launch_bounds__(256) void flash_attn_k(
    const u16* __restrict__ Q, const u16* __restrict__ K, const u16* __restrict__ V,
    u16* __restrict__ av)
{
  __shared__ __align__(16) u16 Kt[64*64];
  __shared__ __align__(16) u16 Vt[64*64];
  __shared__ __align__(16) u16 Pt[4][16*64];

  const int t = threadIdx.x;
  const int w = t >> 6, lane = t & 63, lg = lane >> 4, lr = lane & 15;
  const int qb = blockIdx.x;       // 0..31
  const int bh = blockIdx.y;       // 0..23
  const u16* Qb = Q + (size_t)bh*SEQ*DKV;
  const u16* Kb = K + (size_t)bh*SEQ*DKV;
  const u16* Vb = V + (size_t)bh*SEQ*DKV;

  const int qrow = qb*64 + w*16 + lr;
  u16x8 qf[2];
  qf[0] = *reinterpret_cast<const u16x8*>(Qb + (size_t)qrow*DKV + lg*8);
  qf[1] = *reinterpret_cast<const u16x8*>(Qb + (size_t)qrow*DKV + 32 + lg*8);

  f32x4 acc[4] = {};
  float mrun[4], lrun[4];
  #pragma unroll
  for (int j = 0; j < 4; ++j) { mrun[j] = -1e30f; lrun[j] = 0.f; }

  for (int kt0 = 0; kt0 < SEQ; kt0 += 64) {
    // stage K tile (swizzled)
    #pragma unroll
    for (int q = 0; q < 2; ++q) {
      int c = q*256 + t;
      int row = c >> 3, sl = c & 7;
      u16x8 v = *reinterpret_cast<const u16x8*>(Kb + (size_t)(kt0+row)*DKV + sl*8);
      *reinterpret_cast<u16x8*>(Kt + row*64 + ((sl ^ (row & 7))*8)) = v;
    }
    // stage V transposed Vt[d][key] (swizzled scatter)
    #pragma unroll
    for (int q = 0; q < 2; ++q) {
      int c = q*256 + t;
      int key = c & 63, db = c >> 6;
      u16x8 v = *reinterpret_cast<const u16x8*>(Vb + (size_t)(kt0+key)*DKV + db*8);
      #pragma unroll
      for (int j = 0; j < 8; ++j) {
        int d = db*8 + j;
        int off = d*64 + (((2*key) ^ ((d & 7) << 4)) >> 1);  // u16 units, swizzle on 16B slots
        Vt[off + (key & 7) - (key & 7)] = v[j];              // = Vt[off]
      }
    }
    __syncthreads();

    // QK^T
    f32x4 s[4];
    #pragma unroll
    for (int fc = 0; fc < 4; ++fc) {
      f32x4 z = {};
      #pragma unroll
      for (int kk = 0; kk < 2; ++kk) {
        int r = fc*16 + lr;
        int slot = (lg + 4*kk) ^ (r & 7);
        u16x8 kf = *reinterpret_cast<const u16x8*>(Kt + r*64 + slot*8);
        z = mfma16(qf[kk], kf, z);
      }
      s[fc] = z;
    }

    // online softmax (base-2); row j of group lg spans 16 lanes (lr)
    float rmax[4];
    #pragma unroll
    for (int j = 0; j < 4; ++j)
      rmax[j] = fmaxf(fmaxf(s[0][j], s[1][j]), fmaxf(s[2][j], s[3][j]));
    #pragma unroll
    for (int msk = 1; msk <= 8; msk <<= 1)
      #pragma unroll
      for (int j = 0; j < 4; ++j)
        rmax[j] = fmaxf(rmax[j], __shfl_xor(rmax[j], msk));

    float corr[4];
    #pragma unroll
    for (int j = 0; j < 4; ++j) {
      float mnew = fmaxf(mrun[j], rmax[j]);
      corr[j] = exp2f(mrun[j] - mnew);
      mrun[j] = mnew;
    }
    float p[4][4];
    float rsum[4] = {0.f, 0.f, 0.f, 0.f};
    #pragma unroll
    for (int fc = 0; fc < 4; ++fc)
      #pragma unroll
      for (int j = 0; j < 4; ++j) {
        p[fc][j] = exp2f(s[fc][j] - mrun[j]);
        rsum[j] += p[fc][j];
      }
    #pragma unroll
    for (int msk = 1; msk <= 8; msk <<= 1)
      #pragma unroll
      for (int j = 0; j < 4; ++j)
        rsum[j] += __shfl_xor(rsum[j], msk);
    #pragma unroll
    for (int j = 0; j < 4; ++j)
      lrun[j] = lrun[j]*corr[j] + rsum[j];
    #pragma unroll
    for (int fc = 0; fc < 4; ++fc)
      #pragma unroll
      for (int j = 0; j < 4; ++j)
        acc[fc][j] *= corr[j];

    // P -> bf16 -> per-wave LDS (swizzled)
    u16* Pw = &Pt[w][0];
    #pragma unroll
    for (int fc = 0; fc < 4; ++fc)
      #pragma unroll
      for (int j = 0; j < 4; ++j) {
        int row = lg*4 + j, col = fc*16 + lr;
        int off = row*64 + (((2*col) ^ ((row & 7) << 4)) >> 1);
        Pw[off] = f2bf(p[fc][j]);
      }

    // FENCE: P writes (and everything) visible before PV fragment reads.
    // Without this, alias analysis may hoist the ds_read above the ds_write.
    __syncthreads();

    // PV: O[q][d] += P[q][k] @ V[k][d]
    const u16* Pws = &Pt[w][0];
    #pragma unroll
    for (int kk = 0; kk < 2; ++kk) {
      int slotp = (lg + 4*kk) ^ (lr & 7);
      u16x8 pf = *reinterpret_cast<const u16x8*>(Pws + lr*64 + slotp*8);
      #pragma unroll
      for (int fc = 0; fc < 4; ++fc) {
        int rv = fc*16 + lr;
        int slotv = (lg + 4*kk) ^ (rv & 7);
        u16x8 vf = *reinterpret_cast<const u16x8*>(Vt + rv*64 + slotv*8);
        acc[fc] = mfma16(pf, vf, acc[fc]);
      }
    }
    __syncthreads();
  }

  // epilogue: av[b][s][h*64+d] bf16
  const int b = bh / HEADS, h = bh % HEADS;
  #pragma unroll
  for (int fc = 0; fc < 4; ++fc)
    #pragma unroll
    for (int j = 0; j < 4; ++j) {
      int rq = qb*64 + w*16 + lg*4 + j;
      int e = h*64 + fc*16 + lr;
      float inv = 1.0f / lrun[j];
      av[(size_t)(b*SEQ + rq)*EMB + e] = f2bf(acc[fc][j] * inv);
    }
}

// ---------------- launcher ----------------
extern "C" void kernel_launch(void* const* d_in, const int* in_sizes, int n_in,
                              void* d_out, int out_size, void* d_ws, size_t ws_size,
                              hipStream_t stream) {
  const float* xq_f = (const float*)d_in[0];
  const float* xk_f = (const float*)d_in[1];
  const float* xv_f = (const float*)d_in[2];
  const float* Wq = (const float*)d_in[3];
  const float* bq = (const float*)d_in[4];
  const float* Wk = (const float*)d_in[5];
  const float* bk = (const float*)d_in[6];
  const float* Wv = (const float*)d_in[7];
  const float* bv = (const float*)d_in[8];
  const float* Wo = (const float*)d_in[9];
  const float* bo = (const float*)d_in[10];

  char* ws = (char*)d_ws;
  const size_t szX = (size_t)NTOK*EMB*2;   // 6291456 B
  const size_t szW = (size_t)EMB*EMB*2;    // 1179648 B
  // Sequentially reused buffers: total ws = 25.1 MB
  u16* X  = (u16*)(ws);                    // activation bf16, then av
  u16* Wb = (u16*)(ws + szX);              // current weight bf16
  u16* Qh = (u16*)(ws + szX + szW);
  u16* Kh = (u16*)(ws + szX + szW + szX);
  u16* Vh = (u16*)(ws + szX + szW + 2*szX);

  // fold score scale (1/8) and log2(e) into the Q projection
  const float csc = 0.125f * 1.4426950408889634f;

  const int n8x = NTOK*EMB/8;   // 393216
  const int n8w = EMB*EMB/8;    // 73728
  dim3 gg(NTOK/64, EMB/128);

  cast_bf16_k<<<dim3((n8w+255)/256), dim3(256), 0, stream>>>(Wq, Wb, n8w, csc);
  cast_bf16_k<<<dim3((n8x+255)/256), dim3(256), 0, stream>>>(xq_f, X, n8x, 1.0f);
  gemm_bt_k<0><<<gg, dim3(256), 0, stream>>>(X, Wb, bq, csc,  Qh);

  cast_bf16_k<<<dim3((n8w+255)/256), dim3(256), 0, stream>>>(Wk, Wb, n8w, 1.0f);
  cast_bf16_k<<<dim3((n8x+255)/256), dim3(256), 0, stream>>>(xk_f, X, n8x, 1.0f);
  gemm_bt_k<0><<<gg, dim3(256), 0, stream>>>(X, Wb, bk, 1.0f, Kh);

  cast_bf16_k<<<dim3((n8w+255)/256), dim3(256), 0, stream>>>(Wv, Wb, n8w, 1.0f);
  cast_bf16_k<<<dim3((n8x+255)/256), dim3(256), 0, stream>>>(xv_f, X, n8x, 1.0f);
  gemm_bt_k<0><<<gg, dim3(256), 0, stream>>>(X, Wb, bv, 1.0f, Vh);

  flash_attn_k<<<dim3(SEQ/64, BATCH*HEADS), dim3(256), 0, stream>>>(Qh, Kh, Vh, X);

  cast_bf16_k<<<dim3((n8w+255)/256), dim3(256), 0, stream>>>(Wo, Wb, n8w, 1.0f);
  gemm_bt_k<1><<<gg, dim3(256), 0, stream>>>(X, Wb, bo, 1.0f, d_out);
}

// Round 3
// 167.994 us; speedup vs baseline: 1.1306x; 1.1306x over previous
//
#include <hip/hip_runtime.h>
#include <hip/hip_bf16.h>

#define EMB 768
#define HEADS 12
#define DKV 64
#define BATCH 2
#define SEQ 2048
#define NTOK (BATCH*SEQ)   // 4096

typedef float f32x4 __attribute__((ext_vector_type(4)));
typedef unsigned short u16;
typedef u16 u16x8 __attribute__((ext_vector_type(8)));
typedef u16 u16x4 __attribute__((ext_vector_type(4)));
typedef __bf16 bf16x8 __attribute__((ext_vector_type(8)));

__device__ __forceinline__ u16 f2bf(float f) {
  union { float f; unsigned u; } v; v.f = f;
  unsigned r = v.u + 0x7FFFu + ((v.u >> 16) & 1u);
  return (u16)(r >> 16);
}

__device__ __forceinline__ f32x4 mfma16(u16x8 a, u16x8 b, f32x4 c) {
  return __builtin_amdgcn_mfma_f32_16x16x32_bf16(
      __builtin_bit_cast(bf16x8, a), __builtin_bit_cast(bf16x8, b), c, 0, 0, 0);
}

// ---------------- cast fp32 -> bf16 (optionally scaled), vectorized ----------------
__global__ void cast_bf16_k(const float* __restrict__ src, u16* __restrict__ dst,
                            int n8, float scale) {
  int i = blockIdx.x * blockDim.x + threadIdx.x;
  int stride = gridDim.x * blockDim.x;
  for (; i < n8; i += stride) {
    float4 a = reinterpret_cast<const float4*>(src)[i*2];
    float4 b = reinterpret_cast<const float4*>(src)[i*2+1];
    u16x8 o;
    o[0]=f2bf(a.x*scale); o[1]=f2bf(a.y*scale); o[2]=f2bf(a.z*scale); o[3]=f2bf(a.w*scale);
    o[4]=f2bf(b.x*scale); o[5]=f2bf(b.y*scale); o[6]=f2bf(b.z*scale); o[7]=f2bf(b.w*scale);
    reinterpret_cast<u16x8*>(dst)[i] = o;
  }
}

// ---------------- GEMM: C[4096,768] = A[4096,768] @ B[768,768]^T + bias ----------------
// BM=64, BN=128, BK=64. 256 threads = 4 waves (2x2), each wave 32x64 out.
// LDS tiles XOR-swizzled: physical_slot = logical_slot ^ (row&7) (16B slots, 128B rows).
// MODE 0: out bf16 head-split [B][H][S][DKV] (+bias*bscale).
// MODE 1: out fp32 [M][EMB] (+bias).
// MODE 2: out bf16 head-split TRANSPOSED [B][H][DKV][SEQ] (V^T for flash PV).
template<int MODE>
__global__ __launch_bounds__(256) void gemm_bt_k(
    const u16* __restrict__ A, const u16* __restrict__ Bm,
    const float* __restrict__ bias, float bscale, void* __restrict__ outp)
{
  __shared__ __align__(16) u16 At[64*64];
  __shared__ __align__(16) u16 Bt[128*64];
  const int t = threadIdx.x;
  const int w = t >> 6, lane = t & 63, lg = lane >> 4, lr = lane & 15;
  const int wr = w >> 1, wc = w & 1;
  const int m0 = blockIdx.x * 64, n0 = blockIdx.y * 128;

  f32x4 acc[2][4] = {};

  for (int kb = 0; kb < EMB; kb += 64) {
    #pragma unroll
    for (int q = 0; q < 2; ++q) {
      int c = q*256 + t;
      int row = c >> 3, sl = c & 7;
      u16x8 v = *reinterpret_cast<const u16x8*>(A + (size_t)(m0+row)*EMB + kb + sl*8);
      *reinterpret_cast<u16x8*>(At + row*64 + ((sl ^ (row & 7))*8)) = v;
    }
    #pragma unroll
    for (int q = 0; q < 4; ++q) {
      int c = q*256 + t;
      int row = c >> 3, sl = c & 7;
      u16x8 v = *reinterpret_cast<const u16x8*>(Bm + (size_t)(n0+row)*EMB + kb + sl*8);
      *reinterpret_cast<u16x8*>(Bt + row*64 + ((sl ^ (row & 7))*8)) = v;
    }
    __syncthreads();

    u16x8 af[2][2], bfr[4][2];
    #pragma unroll
    for (int fm = 0; fm < 2; ++fm)
      #pragma unroll
      for (int kk = 0; kk < 2; ++kk) {
        int r = wr*32 + fm*16 + lr;
        int slot = (lg + 4*kk) ^ (r & 7);
        af[fm][kk] = *reinterpret_cast<const u16x8*>(At + r*64 + slot*8);
      }
    #pragma unroll
    for (int fn = 0; fn < 4; ++fn)
      #pragma unroll
      for (int kk = 0; kk < 2; ++kk) {
        int r = wc*64 + fn*16 + lr;
        int slot = (lg + 4*kk) ^ (r & 7);
        bfr[fn][kk] = *reinterpret_cast<const u16x8*>(Bt + r*64 + slot*8);
      }
    #pragma unroll
    for (int fm = 0; fm < 2; ++fm)
      #pragma unroll
      for (int fn = 0; fn < 4; ++fn)
        #pragma unroll
        for (int kk = 0; kk < 2; ++kk)
          acc[fm][fn] = mfma16(af[fm][kk], bfr[fn][kk], acc[fm][fn]);
    __syncthreads();
  }

  // epilogue: C layout col = lane&15, row = (lane>>4)*4 + j  [measured m89]
  #pragma unroll
  for (int fm = 0; fm < 2; ++fm)
    #pragma unroll
    for (int fn = 0; fn < 4; ++fn) {
      const int mb = m0 + wr*32 + fm*16 + lg*4;      // rows mb..mb+3 (j)
      const int e  = n0 + wc*64 + fn*16 + lr;
      if (MODE == 2) {
        int bb = mb >> 11, sb = mb & 2047, h = e >> 6, d = e & 63;
        u16x4 o4;
        #pragma unroll
        for (int j = 0; j < 4; ++j) o4[j] = f2bf(acc[fm][fn][j] + bias[e]*bscale);
        *reinterpret_cast<u16x4*>(
            reinterpret_cast<u16*>(outp) + (((size_t)(bb*HEADS+h))*DKV + d)*SEQ + sb) = o4;
      } else {
        #pragma unroll
        for (int j = 0; j < 4; ++j) {
          int m = mb + j;
          float val = acc[fm][fn][j] + bias[e]*bscale;
          if (MODE == 0) {
            int bb = m >> 11, s = m & 2047, h = e >> 6, d = e & 63;
            reinterpret_cast<u16*>(outp)[(((size_t)(bb*HEADS+h))*SEQ + s)*DKV + d] = f2bf(val);
          } else {
            reinterpret_cast<float*>(outp)[(size_t)m*EMB + e] = val;
          }
        }
      }
    }
}

// ---------------- flash attention (swapped-QK^T, per-lane softmax) ----------------
// Q pre-scaled by 0.125*log2(e) -> base-2 softmax.
// 4 waves x 16 q-rows. S^T = mfma(K,Q): lane owns ONE q-row (col=lane&15),
// holds 16 of 64 keys; reduce = 15 local fmax + 2 shfl_xor. P stored j-contiguous
// (4x ds_write_b64) into per-wave swizzled [16q][64k] tile; PV computes
// O^T = mfma(V^T, P) from the V^T-layout global produced by the V projection.
__global__ __launch_bounds__(256) void flash_attn_k(
    const u16* __restrict__ Q, const u16* __restrict__ K, const u16* __restrict__ VT,
    u16* __restrict__ av)
{
  __shared__ __align__(16) u16 Kt[64*64];       // [key][d] swizzled
  __shared__ __align__(16) u16 Vt[64*64];       // [d][key] swizzled
  __shared__ __align__(16) u16 Pt[4][16*64];    // per-wave [q][k] swizzled (8B slots)

  const int t = threadIdx.x;
  const int w = t >> 6, lane = t & 63, lg = lane >> 4, lr = lane & 15;
  const int qb = blockIdx.x;       // 0..31
  const int bh = blockIdx.y;       // 0..23
  const u16* Qb = Q  + (size_t)bh*SEQ*DKV;
  const u16* Kb = K  + (size_t)bh*SEQ*DKV;
  const u16* Vb = VT + (size_t)bh*DKV*SEQ;

  // Q B-fragment: col=q=lr, elements d = lg*8 + 32*kk (+0..7)
  const int qrow = qb*64 + w*16 + lr;
  u16x8 qf[2];
  qf[0] = *reinterpret_cast<const u16x8*>(Qb + (size_t)qrow*DKV + lg*8);
  qf[1] = *reinterpret_cast<const u16x8*>(Qb + (size_t)qrow*DKV + 32 + lg*8);

  f32x4 acc[4] = {};   // O^T accum: acc[fc][j] -> d = fc*16+lg*4+j, q = lr
  float mrun = -1e30f, lrun = 0.f;

  for (int kt0 = 0; kt0 < SEQ; kt0 += 64) {
    // stage K tile [key][d] (swizzled, vector)
    #pragma unroll
    for (int q = 0; q < 2; ++q) {
      int c = q*256 + t;
      int row = c >> 3, sl = c & 7;
      u16x8 v = *reinterpret_cast<const u16x8*>(Kb + (size_t)(kt0+row)*DKV + sl*8);
      *reinterpret_cast<u16x8*>(Kt + row*64 + ((sl ^ (row & 7))*8)) = v;
    }
    // stage V^T tile [d][key] (swizzled, vector — global is already V^T)
    #pragma unroll
    for (int q = 0; q < 2; ++q) {
      int c = q*256 + t;
      int d = c >> 3, sl = c & 7;
      u16x8 v = *reinterpret_cast<const u16x8*>(Vb + (size_t)d*SEQ + kt0 + sl*8);
      *reinterpret_cast<u16x8*>(Vt + d*64 + ((sl ^ (d & 7))*8)) = v;
    }
    __syncthreads();

    // S^T[key][q] = mfma(K, Q): s[fc] rows = keys fc*16+lg*4+j, col = q = lr
    f32x4 s[4];
    #pragma unroll
    for (int fc = 0; fc < 4; ++fc) {
      f32x4 z = {};
      #pragma unroll
      for (int kk = 0; kk < 2; ++kk) {
        int r = fc*16 + lr;
        int slot = (lg + 4*kk) ^ (r & 7);
        u16x8 kf = *reinterpret_cast<const u16x8*>(Kt + r*64 + slot*8);
        z = mfma16(kf, qf[kk], z);
      }
      s[fc] = z;
    }

    // per-lane online softmax (lane owns q=lr; 16 of 64 keys local)
    float pmax = s[0][0];
    #pragma unroll
    for (int fc = 0; fc < 4; ++fc)
      #pragma unroll
      for (int j = 0; j < 4; ++j)
        pmax = fmaxf(pmax, s[fc][j]);
    pmax = fmaxf(pmax, __shfl_xor(pmax, 16));
    pmax = fmaxf(pmax, __shfl_xor(pmax, 32));

    float mnew = fmaxf(mrun, pmax);
    float corr = exp2f(mrun - mnew);
    mrun = mnew;

    float p[4][4];
    float rsum = 0.f;
    #pragma unroll
    for (int fc = 0; fc < 4; ++fc)
      #pragma unroll
      for (int j = 0; j < 4; ++j) {
        p[fc][j] = exp2f(s[fc][j] - mrun);
        rsum += p[fc][j];
      }
    rsum += __shfl_xor(rsum, 16);
    rsum += __shfl_xor(rsum, 32);
    lrun = lrun*corr + rsum;
    #pragma unroll
    for (int fc = 0; fc < 4; ++fc)
      #pragma unroll
      for (int j = 0; j < 4; ++j)
        acc[fc][j] *= corr;

    // P -> bf16, j-contiguous in k: one 8B store per fc into per-wave tile.
    // Layout P[q=lr][k], 8B slots s8 = k/4, phys8 = s8 ^ ((lr&7)<<1).
    char* Pw = reinterpret_cast<char*>(&Pt[w][0]);
    #pragma unroll
    for (int fc = 0; fc < 4; ++fc) {
      u16x4 q4;
      #pragma unroll
      for (int j = 0; j < 4; ++j) q4[j] = f2bf(p[fc][j]);
      *reinterpret_cast<u16x4*>(Pw + lr*128 + (((fc*4 + lg) ^ ((lr & 7) << 1))*8)) = q4;
    }

    // same-wave LDS RAW fence (no block barrier needed for per-wave Pt)
    asm volatile("s_waitcnt lgkmcnt(0)" ::: "memory");
    __builtin_amdgcn_sched_barrier(0);

    // PV: O^T[d][q] += V^T[d][k] * P^T[k][q]  -> mfma(vf, pf)
    #pragma unroll
    for (int kk = 0; kk < 2; ++kk) {
      u16x8 pf = *reinterpret_cast<const u16x8*>(
          Pw + lr*128 + (((kk*8 + lg*2) ^ ((lr & 7) << 1))*8));
      #pragma unroll
      for (int fc = 0; fc < 4; ++fc) {
        int rv = fc*16 + lr;
        int slotv = (lg + 4*kk) ^ (rv & 7);
        u16x8 vf = *reinterpret_cast<const u16x8*>(Vt + rv*64 + slotv*8);
        acc[fc] = mfma16(vf, pf, acc[fc]);
      }
    }
    __syncthreads();
  }

  // epilogue: lane owns q=qrow; d = fc*16+lg*4+j contiguous -> 8B stores
  const int b = bh / HEADS, h = bh % HEADS;
  const float inv = 1.0f / lrun;
  #pragma unroll
  for (int fc = 0; fc < 4; ++fc) {
    u16x4 o4;
    #pragma unroll
    for (int j = 0; j < 4; ++j) o4[j] = f2bf(acc[fc][j] * inv);
    *reinterpret_cast<u16x4*>(
        av + ((size_t)(b*SEQ + qrow))*EMB + h*64 + fc*16 + lg*4) = o4;
  }
}

// ---------------- launcher ----------------
extern "C" void kernel_launch(void* const* d_in, const int* in_sizes, int n_in,
                              void* d_out, int out_size, void* d_ws, size_t ws_size,
                              hipStream_t stream) {
  const float* xq_f = (const float*)d_in[0];
  const float* xk_f = (const float*)d_in[1];
  const float* xv_f = (const float*)d_in[2];
  const float* Wq = (const float*)d_in[3];
  const float* bq = (const float*)d_in[4];
  const float* Wk = (const float*)d_in[5];
  const float* bk = (const float*)d_in[6];
  const float* Wv = (const float*)d_in[7];
  const float* bv = (const float*)d_in[8];
  const float* Wo = (const float*)d_in[9];
  const float* bo = (const float*)d_in[10];

  char* ws = (char*)d_ws;
  const size_t szX = (size_t)NTOK*EMB*2;   // 6291456 B
  const size_t szW = (size_t)EMB*EMB*2;    // 1179648 B
  u16* X  = (u16*)(ws);                    // activation bf16, then av
  u16* Wb = (u16*)(ws + szX);              // current weight bf16
  u16* Qh = (u16*)(ws + szX + szW);
  u16* Kh = (u16*)(ws + szX + szW + szX);
  u16* Vh = (u16*)(ws + szX + szW + 2*szX);   // V^T layout [B][H][DKV][SEQ]

  const float csc = 0.125f * 1.4426950408889634f;  // score scale folded into Q proj

  const int n8x = NTOK*EMB/8;
  const int n8w = EMB*EMB/8;
  dim3 gg(NTOK/64, EMB/128);

  cast_bf16_k<<<dim3((n8w+255)/256), dim3(256), 0, stream>>>(Wq, Wb, n8w, csc);
  cast_bf16_k<<<dim3((n8x+255)/256), dim3(256), 0, stream>>>(xq_f, X, n8x, 1.0f);
  gemm_bt_k<0><<<gg, dim3(256), 0, stream>>>(X, Wb, bq, csc,  Qh);

  cast_bf16_k<<<dim3((n8w+255)/256), dim3(256), 0, stream>>>(Wk, Wb, n8w, 1.0f);
  cast_bf16_k<<<dim3((n8x+255)/256), dim3(256), 0, stream>>>(xk_f, X, n8x, 1.0f);
  gemm_bt_k<0><<<gg, dim3(256), 0, stream>>>(X, Wb, bk, 1.0f, Kh);

  cast_bf16_k<<<dim3((n8w+255)/256), dim3(256), 0, stream>>>(Wv, Wb, n8w, 1.0f);
  cast_bf16_k<<<dim3((n8x+255)/256), dim3(256), 0, stream>>>(xv_f, X, n8x, 1.0f);
  gemm_bt_k<2><<<gg, dim3(256), 0, stream>>>(X, Wb, bv, 1.0f, Vh);

  flash_attn_k<<<dim3(SEQ/64, BATCH*HEADS), dim3(256), 0, stream>>>(Qh, Kh, Vh, X);

  cast_bf16_k<<<dim3((n8w+255)/256), dim3(256), 0, stream>>>(Wo, Wb, n8w, 1.0f);
  gemm_bt_k<1><<<gg, dim3(256), 0, stream>>>(X, Wb, bo, 1.0f, d_out);
}

// Round 4
// 128.321 us; speedup vs baseline: 1.4801x; 1.3092x over previous
//
#include <hip/hip_runtime.h>
#include <hip/hip_bf16.h>

#define EMB 768
#define HEADS 12
#define DKV 64
#define BATCH 2
#define SEQ 2048
#define NTOK (BATCH*SEQ)   // 4096

typedef float f32x4 __attribute__((ext_vector_type(4)));
typedef unsigned short u16;
typedef u16 u16x8 __attribute__((ext_vector_type(8)));
typedef u16 u16x4 __attribute__((ext_vector_type(4)));
typedef __bf16 bf16x8 __attribute__((ext_vector_type(8)));

// native f32->bf16 (RNE via v_cvt_pk_bf16_f32; compiler packs pairs — m240)
__device__ __forceinline__ u16 f2bf(float f) {
  return __builtin_bit_cast(u16, (__bf16)f);
}

__device__ __forceinline__ f32x4 mfma16(u16x8 a, u16x8 b, f32x4 c) {
  return __builtin_amdgcn_mfma_f32_16x16x32_bf16(
      __builtin_bit_cast(bf16x8, a), __builtin_bit_cast(bf16x8, b), c, 0, 0, 0);
}

// ---------------- GEMM: C[4096,768] = A[4096,768] @ W[768,768]^T + bias ----------------
// BM=64, BN=128, BK=64; 4 waves (2x2). Fp32 inputs cast in-register during staging
// (AF32) — no separate cast kernels. Double-buffered LDS, ONE barrier per K-step:
// within an iteration reads hit buf[cur], writes hit buf[cur^1] (disjoint); the
// barrier separates iterations. Loads for step t+1 issue before compute of t (T14).
// MODE 0: out bf16 head-split [B][H][S][DKV]. MODE 1: out fp32 [M][EMB].
// MODE 2: out bf16 head-split transposed [B][H][DKV][SEQ] (V^T for flash).
template<int MODE, bool AF32>
__global__ __launch_bounds__(256) void gemm_bt_k(
    const void* __restrict__ Ap, const float* __restrict__ Bm,
    const float* __restrict__ bias, float ascale, float bscale,
    void* __restrict__ outp)
{
  __shared__ __align__(16) u16 At[2][64*64];
  __shared__ __align__(16) u16 Bt[2][128*64];
  const int t = threadIdx.x;
  const int w = t >> 6, lane = t & 63, lg = lane >> 4, lr = lane & 15;
  const int wr = w >> 1, wc = w & 1;
  const int m0 = blockIdx.x * 64, n0 = blockIdx.y * 128;

  f32x4 acc[2][4] = {};
  f32x4 raf[2][2];   // fp32 A staging regs
  u16x8 rab[2];      // bf16 A staging regs
  f32x4 rbf[4][2];   // fp32 B staging regs

  auto STAGE_LOAD = [&](int kb) {
    #pragma unroll
    for (int q = 0; q < 2; ++q) {
      int c = q*256 + t, row = c >> 3, sl = c & 7;
      if constexpr (AF32) {
        const float* p = (const float*)Ap + (size_t)(m0+row)*EMB + kb + sl*8;
        raf[q][0] = *reinterpret_cast<const f32x4*>(p);
        raf[q][1] = *reinterpret_cast<const f32x4*>(p + 4);
      } else {
        rab[q] = *reinterpret_cast<const u16x8*>(
            (const u16*)Ap + (size_t)(m0+row)*EMB + kb + sl*8);
      }
    }
    #pragma unroll
    for (int q = 0; q < 4; ++q) {
      int c = q*256 + t, row = c >> 3, sl = c & 7;
      const float* p = Bm + (size_t)(n0+row)*EMB + kb + sl*8;
      rbf[q][0] = *reinterpret_cast<const f32x4*>(p);
      rbf[q][1] = *reinterpret_cast<const f32x4*>(p + 4);
    }
  };

  auto STAGE_WRITE = [&](int bi) {
    #pragma unroll
    for (int q = 0; q < 2; ++q) {
      int c = q*256 + t, row = c >> 3, sl = c & 7;
      u16x8 v;
      if constexpr (AF32) {
        #pragma unroll
        for (int j = 0; j < 4; ++j) {
          v[j]   = f2bf(raf[q][0][j] * ascale);
          v[4+j] = f2bf(raf[q][1][j] * ascale);
        }
      } else v = rab[q];
      *reinterpret_cast<u16x8*>(&At[bi][row*64 + ((sl ^ (row & 7))*8)]) = v;
    }
    #pragma unroll
    for (int q = 0; q < 4; ++q) {
      int c = q*256 + t, row = c >> 3, sl = c & 7;
      u16x8 v;
      #pragma unroll
      for (int j = 0; j < 4; ++j) {
        v[j]   = f2bf(rbf[q][0][j]);
        v[4+j] = f2bf(rbf[q][1][j]);
      }
      *reinterpret_cast<u16x8*>(&Bt[bi][row*64 + ((sl ^ (row & 7))*8)]) = v;
    }
  };

  auto COMPUTE = [&](int bi) {
    u16x8 af[2][2], bfr[4][2];
    #pragma unroll
    for (int fm = 0; fm < 2; ++fm)
      #pragma unroll
      for (int kk = 0; kk < 2; ++kk) {
        int r = wr*32 + fm*16 + lr;
        int slot = (lg + 4*kk) ^ (r & 7);
        af[fm][kk] = *reinterpret_cast<const u16x8*>(&At[bi][r*64 + slot*8]);
      }
    #pragma unroll
    for (int fn = 0; fn < 4; ++fn)
      #pragma unroll
      for (int kk = 0; kk < 2; ++kk) {
        int r = wc*64 + fn*16 + lr;
        int slot = (lg + 4*kk) ^ (r & 7);
        bfr[fn][kk] = *reinterpret_cast<const u16x8*>(&Bt[bi][r*64 + slot*8]);
      }
    #pragma unroll
    for (int fm = 0; fm < 2; ++fm)
      #pragma unroll
      for (int fn = 0; fn < 4; ++fn)
        #pragma unroll
        for (int kk = 0; kk < 2; ++kk)
          acc[fm][fn] = mfma16(af[fm][kk], bfr[fn][kk], acc[fm][fn]);
  };

  STAGE_LOAD(0);
  STAGE_WRITE(0);
  __syncthreads();
  int cur = 0;
  const int NSTEP = EMB/64;   // 12
  for (int ts = 0; ts < NSTEP-1; ++ts) {
    STAGE_LOAD((ts+1)*64);
    COMPUTE(cur);
    STAGE_WRITE(cur ^ 1);
    __syncthreads();
    cur ^= 1;
  }
  COMPUTE(cur);

  // epilogue: C layout col = lane&15, row = (lane>>4)*4 + j  [measured m89]
  #pragma unroll
  for (int fm = 0; fm < 2; ++fm)
    #pragma unroll
    for (int fn = 0; fn < 4; ++fn) {
      const int mb = m0 + wr*32 + fm*16 + lg*4;
      const int e  = n0 + wc*64 + fn*16 + lr;
      if (MODE == 2) {
        int bb = mb >> 11, sb = mb & 2047, h = e >> 6, d = e & 63;
        u16x4 o4;
        #pragma unroll
        for (int j = 0; j < 4; ++j) o4[j] = f2bf(acc[fm][fn][j] + bias[e]*bscale);
        *reinterpret_cast<u16x4*>(
            reinterpret_cast<u16*>(outp) + (((size_t)(bb*HEADS+h))*DKV + d)*SEQ + sb) = o4;
      } else {
        #pragma unroll
        for (int j = 0; j < 4; ++j) {
          int m = mb + j;
          float val = acc[fm][fn][j] + bias[e]*bscale;
          if (MODE == 0) {
            int bb = m >> 11, s = m & 2047, h = e >> 6, d = e & 63;
            reinterpret_cast<u16*>(outp)[(((size_t)(bb*HEADS+h))*SEQ + s)*DKV + d] = f2bf(val);
          } else {
            reinterpret_cast<float*>(outp)[(size_t)m*EMB + e] = val;
          }
        }
      }
    }
}

// ---------------- flash attention (swapped-QK^T, per-lane softmax) ----------------
// Q pre-scaled by 0.125*log2(e) -> base-2 softmax. 4 waves x 16 q-rows.
// K/V double-buffered in LDS, ONE barrier per tile, loads issued before compute
// (T14). Defer-rescale (T13, THR=8). P per-wave swizzled tile + lgkmcnt fence.
__global__ __launch_bounds__(256) void flash_attn_k(
    const u16* __restrict__ Q, const u16* __restrict__ K, const u16* __restrict__ VT,
    u16* __restrict__ av)
{
  __shared__ __align__(16) u16 Kt[2][64*64];     // [key][d] swizzled
  __shared__ __align__(16) u16 Vt[2][64*64];     // [d][key] swizzled
  __shared__ __align__(16) u16 Pt[4][16*64];     // per-wave [q][k] swizzled

  const int t = threadIdx.x;
  const int w = t >> 6, lane = t & 63, lg = lane >> 4, lr = lane & 15;
  const int qb = blockIdx.x;       // 0..31
  const int bh = blockIdx.y;       // 0..23
  const u16* Qb = Q  + (size_t)bh*SEQ*DKV;
  const u16* Kb = K  + (size_t)bh*SEQ*DKV;
  const u16* Vb = VT + (size_t)bh*DKV*SEQ;

  const int qrow = qb*64 + w*16 + lr;
  u16x8 qf[2];
  qf[0] = *reinterpret_cast<const u16x8*>(Qb + (size_t)qrow*DKV + lg*8);
  qf[1] = *reinterpret_cast<const u16x8*>(Qb + (size_t)qrow*DKV + 32 + lg*8);

  f32x4 acc[4] = {};   // O^T: acc[fc][j] -> d = fc*16+lg*4+j, q = lr
  float mrun = -1e30f, lrun = 0.f;

  u16x8 ks[2], vs[2];
  auto LOADKV = [&](int kt0) {
    #pragma unroll
    for (int q = 0; q < 2; ++q) {
      int c = q*256 + t, row = c >> 3, sl = c & 7;
      ks[q] = *reinterpret_cast<const u16x8*>(Kb + (size_t)(kt0+row)*DKV + sl*8);
    }
    #pragma unroll
    for (int q = 0; q < 2; ++q) {
      int c = q*256 + t, d = c >> 3, sl = c & 7;
      vs[q] = *reinterpret_cast<const u16x8*>(Vb + (size_t)d*SEQ + kt0 + sl*8);
    }
  };
  auto WRITEKV = [&](int bi) {
    #pragma unroll
    for (int q = 0; q < 2; ++q) {
      int c = q*256 + t, row = c >> 3, sl = c & 7;
      *reinterpret_cast<u16x8*>(&Kt[bi][row*64 + ((sl ^ (row & 7))*8)]) = ks[q];
    }
    #pragma unroll
    for (int q = 0; q < 2; ++q) {
      int c = q*256 + t, d = c >> 3, sl = c & 7;
      *reinterpret_cast<u16x8*>(&Vt[bi][d*64 + ((sl ^ (d & 7))*8)]) = vs[q];
    }
  };

  LOADKV(0);
  WRITEKV(0);
  __syncthreads();
  int cur = 0;
  const int NT = SEQ/64;   // 32

  for (int kt = 0; kt < NT; ++kt) {
    if (kt+1 < NT) LOADKV((kt+1)*64);   // issue early; latency hides under compute

    // S^T[key][q] = mfma(K, Q): rows = keys fc*16+lg*4+j, col = q = lr
    f32x4 s[4];
    #pragma unroll
    for (int fc = 0; fc < 4; ++fc) {
      f32x4 z = {};
      #pragma unroll
      for (int kk = 0; kk < 2; ++kk) {
        int r = fc*16 + lr;
        int slot = (lg + 4*kk) ^ (r & 7);
        u16x8 kf = *reinterpret_cast<const u16x8*>(&Kt[cur][r*64 + slot*8]);
        z = mfma16(kf, qf[kk], z);
      }
      s[fc] = z;
    }

    // per-lane online softmax; max tree shaped for v_max3 fusion
    float pmax = fmaxf(fmaxf(s[0][0], s[0][1]), s[0][2]);
    pmax = fmaxf(fmaxf(pmax, s[0][3]), s[1][0]);
    pmax = fmaxf(fmaxf(pmax, s[1][1]), s[1][2]);
    pmax = fmaxf(fmaxf(pmax, s[1][3]), s[2][0]);
    pmax = fmaxf(fmaxf(pmax, s[2][1]), s[2][2]);
    pmax = fmaxf(fmaxf(pmax, s[2][3]), s[3][0]);
    pmax = fmaxf(fmaxf(pmax, s[3][1]), s[3][2]);
    pmax = fmaxf(pmax, s[3][3]);
    pmax = fmaxf(pmax, __shfl_xor(pmax, 16));
    pmax = fmaxf(pmax, __shfl_xor(pmax, 32));

    // defer-rescale (T13): skip O/l rescale unless max grew past THR=8
    if (!__all(pmax <= mrun + 8.f)) {
      float mnew = fmaxf(mrun, pmax);
      float corr = exp2f(mrun - mnew);
      mrun = mnew;
      lrun *= corr;
      #pragma unroll
      for (int fc = 0; fc < 4; ++fc)
        #pragma unroll
        for (int j = 0; j < 4; ++j)
          acc[fc][j] *= corr;
    }

    float p[4][4];
    float rsum = 0.f;
    #pragma unroll
    for (int fc = 0; fc < 4; ++fc)
      #pragma unroll
      for (int j = 0; j < 4; ++j) {
        p[fc][j] = exp2f(s[fc][j] - mrun);
        rsum += p[fc][j];
      }
    rsum += __shfl_xor(rsum, 16);
    rsum += __shfl_xor(rsum, 32);
    lrun += rsum;

    // P -> bf16, j-contiguous in k: one 8B store per fc into per-wave tile
    char* Pw = reinterpret_cast<char*>(&Pt[w][0]);
    #pragma unroll
    for (int fc = 0; fc < 4; ++fc) {
      u16x4 q4;
      #pragma unroll
      for (int j = 0; j < 4; ++j) q4[j] = f2bf(p[fc][j]);
      *reinterpret_cast<u16x4*>(Pw + lr*128 + (((fc*4 + lg) ^ ((lr & 7) << 1))*8)) = q4;
    }

    // same-wave LDS RAW fence (per-wave Pt; no block barrier needed)
    asm volatile("s_waitcnt lgkmcnt(0)" ::: "memory");
    __builtin_amdgcn_sched_barrier(0);

    // PV: O^T[d][q] += V^T[d][k] * P^T[k][q]
    #pragma unroll
    for (int kk = 0; kk < 2; ++kk) {
      u16x8 pf = *reinterpret_cast<const u16x8*>(
          Pw + lr*128 + (((kk*8 + lg*2) ^ ((lr & 7) << 1))*8));
      #pragma unroll
      for (int fc = 0; fc < 4; ++fc) {
        int rv = fc*16 + lr;
        int slotv = (lg + 4*kk) ^ (rv & 7);
        u16x8 vf = *reinterpret_cast<const u16x8*>(&Vt[cur][rv*64 + slotv*8]);
        acc[fc] = mfma16(vf, pf, acc[fc]);
      }
    }

    if (kt+1 < NT) WRITEKV(cur ^ 1);    // disjoint buffer from this tile's reads
    __syncthreads();                     // one barrier per tile
    cur ^= 1;
  }

  // epilogue: lane owns q=qrow; d contiguous -> 8B stores
  const int b = bh / HEADS, h = bh % HEADS;
  const float inv = 1.0f / lrun;
  #pragma unroll
  for (int fc = 0; fc < 4; ++fc) {
    u16x4 o4;
    #pragma unroll
    for (int j = 0; j < 4; ++j) o4[j] = f2bf(acc[fc][j] * inv);
    *reinterpret_cast<u16x4*>(
        av + ((size_t)(b*SEQ + qrow))*EMB + h*64 + fc*16 + lg*4) = o4;
  }
}

// ---------------- launcher: 5 kernels, no cast pass ----------------
extern "C" void kernel_launch(void* const* d_in, const int* in_sizes, int n_in,
                              void* d_out, int out_size, void* d_ws, size_t ws_size,
                              hipStream_t stream) {
  const float* xq_f = (const float*)d_in[0];
  const float* xk_f = (const float*)d_in[1];
  const float* xv_f = (const float*)d_in[2];
  const float* Wq = (const float*)d_in[3];
  const float* bq = (const float*)d_in[4];
  const float* Wk = (const float*)d_in[5];
  const float* bk = (const float*)d_in[6];
  const float* Wv = (const float*)d_in[7];
  const float* bv = (const float*)d_in[8];
  const float* Wo = (const float*)d_in[9];
  const float* bo = (const float*)d_in[10];

  u16* Qh = (u16*)d_ws;                       // [B][H][S][DKV] bf16
  u16* Kh = Qh + (size_t)NTOK*EMB;
  u16* Vh = Kh + (size_t)NTOK*EMB;            // [B][H][DKV][SEQ] bf16 (V^T)
  u16* Xb = Vh + (size_t)NTOK*EMB;            // attention output bf16

  const float csc = 0.125f * 1.4426950408889634f;  // score scale, folded into Q proj

  dim3 gg(NTOK/64, EMB/128);
  gemm_bt_k<0,true ><<<gg, dim3(256), 0, stream>>>(xq_f, Wq, bq, csc, csc, Qh);
  gemm_bt_k<0,true ><<<gg, dim3(256), 0, stream>>>(xk_f, Wk, bk, 1.f, 1.f, Kh);
  gemm_bt_k<2,true ><<<gg, dim3(256), 0, stream>>>(xv_f, Wv, bv, 1.f, 1.f, Vh);

  flash_attn_k<<<dim3(SEQ/64, BATCH*HEADS), dim3(256), 0, stream>>>(Qh, Kh, Vh, Xb);

  gemm_bt_k<1,false><<<gg, dim3(256), 0, stream>>>(Xb, Wo, bo, 1.f, 1.f, d_out);
}

// Round 5
// 103.630 us; speedup vs baseline: 1.8327x; 1.2383x over previous
//
#include <hip/hip_runtime.h>
#include <hip/hip_bf16.h>

#define EMB 768
#define HEADS 12
#define DKV 64
#define BATCH 2
#define SEQ 2048
#define NTOK (BATCH*SEQ)   // 4096

typedef float f32x4 __attribute__((ext_vector_type(4)));
typedef unsigned short u16;
typedef u16 u16x8 __attribute__((ext_vector_type(8)));
typedef u16 u16x4 __attribute__((ext_vector_type(4)));
typedef __bf16 bf16x8 __attribute__((ext_vector_type(8)));

// native f32->bf16 RNE (compiler emits v_cvt_pk_bf16_f32 for pairs — m240)
__device__ __forceinline__ u16 f2bf(float f) {
  return __builtin_bit_cast(u16, (__bf16)f);
}

// single-instruction v_exp_f32 (2^x, ~1ulp) — avoids OCML guarded expansion
__device__ __forceinline__ float fexp2(float x) {
#if __has_builtin(__builtin_amdgcn_exp2f)
  return __builtin_amdgcn_exp2f(x);
#else
  return exp2f(x);
#endif
}

__device__ __forceinline__ f32x4 mfma16(u16x8 a, u16x8 b, f32x4 c) {
  return __builtin_amdgcn_mfma_f32_16x16x32_bf16(
      __builtin_bit_cast(bf16x8, a), __builtin_bit_cast(bf16x8, b), c, 0, 0, 0);
}

// ---------------- GEMM core: C[4096,768] = A @ W^T + bias ----------------
// BM=64, BN=128, BK=64; 4 waves (2x2). AF32: fp32 A cast in-register during staging.
// Double-buffered LDS, ONE barrier per K-step, K-loop FULLY UNROLLED (buffer index
// compile-time -> all LDS addresses fold to base+imm).
// MODE 0: bf16 head-split [B][H][S][DKV]. MODE 1: fp32 [M][EMB].
// MODE 2: bf16 head-split transposed [B][H][DKV][SEQ].
template<int MODE, bool AF32>
__device__ __forceinline__ void gemm_core(
    const void* __restrict__ Ap, const float* __restrict__ Bm,
    const float* __restrict__ bias, float ascale, float bscale,
    void* __restrict__ outp, u16* __restrict__ At, u16* __restrict__ Bt,
    int m0, int n0)
{
  const int t = threadIdx.x;
  const int w = t >> 6, lane = t & 63, lg = lane >> 4, lr = lane & 15;
  const int wr = w >> 1, wc = w & 1;
  const int tr = t >> 3, tsl = t & 7;   // staging row/slot

  f32x4 acc[2][4] = {};
  f32x4 raf[2][2];
  u16x8 rab[2];
  f32x4 rbf[4][2];

  auto STAGE_LOAD = [&](int kb) {
    #pragma unroll
    for (int q = 0; q < 2; ++q) {
      int row = q*32 + tr;
      if constexpr (AF32) {
        const float* p = (const float*)Ap + (size_t)(m0+row)*EMB + kb + tsl*8;
        raf[q][0] = *reinterpret_cast<const f32x4*>(p);
        raf[q][1] = *reinterpret_cast<const f32x4*>(p + 4);
      } else {
        rab[q] = *reinterpret_cast<const u16x8*>(
            (const u16*)Ap + (size_t)(m0+row)*EMB + kb + tsl*8);
      }
    }
    #pragma unroll
    for (int q = 0; q < 4; ++q) {
      int row = q*32 + tr;
      const float* p = Bm + (size_t)(n0+row)*EMB + kb + tsl*8;
      rbf[q][0] = *reinterpret_cast<const f32x4*>(p);
      rbf[q][1] = *reinterpret_cast<const f32x4*>(p + 4);
    }
  };

  auto STAGE_WRITE = [&](int bi) {
    #pragma unroll
    for (int q = 0; q < 2; ++q) {
      int row = q*32 + tr;
      u16x8 v;
      if constexpr (AF32) {
        #pragma unroll
        for (int j = 0; j < 4; ++j) {
          v[j]   = f2bf(raf[q][0][j] * ascale);
          v[4+j] = f2bf(raf[q][1][j] * ascale);
        }
      } else v = rab[q];
      *reinterpret_cast<u16x8*>(&At[bi*4096 + row*64 + ((tsl ^ (row & 7))*8)]) = v;
    }
    #pragma unroll
    for (int q = 0; q < 4; ++q) {
      int row = q*32 + tr;
      u16x8 v;
      #pragma unroll
      for (int j = 0; j < 4; ++j) {
        v[j]   = f2bf(rbf[q][0][j]);
        v[4+j] = f2bf(rbf[q][1][j]);
      }
      *reinterpret_cast<u16x8*>(&Bt[bi*8192 + row*64 + ((tsl ^ (row & 7))*8)]) = v;
    }
  };

  auto COMPUTE = [&](int bi) {
    u16x8 af[2][2], bfr[4][2];
    #pragma unroll
    for (int fm = 0; fm < 2; ++fm)
      #pragma unroll
      for (int kk = 0; kk < 2; ++kk) {
        int r = wr*32 + fm*16 + lr;
        int slot = (lg + 4*kk) ^ (r & 7);
        af[fm][kk] = *reinterpret_cast<const u16x8*>(&At[bi*4096 + r*64 + slot*8]);
      }
    #pragma unroll
    for (int fn = 0; fn < 4; ++fn)
      #pragma unroll
      for (int kk = 0; kk < 2; ++kk) {
        int r = wc*64 + fn*16 + lr;
        int slot = (lg + 4*kk) ^ (r & 7);
        bfr[fn][kk] = *reinterpret_cast<const u16x8*>(&Bt[bi*8192 + r*64 + slot*8]);
      }
    __builtin_amdgcn_s_setprio(1);
    #pragma unroll
    for (int fm = 0; fm < 2; ++fm)
      #pragma unroll
      for (int fn = 0; fn < 4; ++fn)
        #pragma unroll
        for (int kk = 0; kk < 2; ++kk)
          acc[fm][fn] = mfma16(af[fm][kk], bfr[fn][kk], acc[fm][fn]);
    __builtin_amdgcn_s_setprio(0);
  };

  STAGE_LOAD(0);
  STAGE_WRITE(0);
  __syncthreads();
  const int NSTEP = EMB/64;   // 12
  #pragma unroll
  for (int ts = 0; ts < NSTEP-1; ++ts) {
    STAGE_LOAD((ts+1)*64);
    COMPUTE(ts & 1);
    STAGE_WRITE((ts & 1) ^ 1);
    __syncthreads();
  }
  COMPUTE((NSTEP-1) & 1);

  // epilogue: C layout col = lane&15, row = (lane>>4)*4 + j  [measured m89]
  #pragma unroll
  for (int fm = 0; fm < 2; ++fm)
    #pragma unroll
    for (int fn = 0; fn < 4; ++fn) {
      const int mb = m0 + wr*32 + fm*16 + lg*4;
      const int e  = n0 + wc*64 + fn*16 + lr;
      if constexpr (MODE == 2) {
        int bb = mb >> 11, sb = mb & 2047, h = e >> 6, d = e & 63;
        u16x4 o4;
        #pragma unroll
        for (int j = 0; j < 4; ++j) o4[j] = f2bf(acc[fm][fn][j] + bias[e]*bscale);
        *reinterpret_cast<u16x4*>(
            reinterpret_cast<u16*>(outp) + (((size_t)(bb*HEADS+h))*DKV + d)*SEQ + sb) = o4;
      } else {
        #pragma unroll
        for (int j = 0; j < 4; ++j) {
          int m = mb + j;
          float val = acc[fm][fn][j] + bias[e]*bscale;
          if constexpr (MODE == 0) {
            int bb = m >> 11, s = m & 2047, h = e >> 6, d = e & 63;
            reinterpret_cast<u16*>(outp)[(((size_t)(bb*HEADS+h))*SEQ + s)*DKV + d] = f2bf(val);
          } else {
            reinterpret_cast<float*>(outp)[(size_t)m*EMB + e] = val;
          }
        }
      }
    }
}

// fused Q/K/V projections: blockIdx.z selects which
__global__ __launch_bounds__(256) void qkv_k(
    const float* __restrict__ Aq, const float* __restrict__ Ak, const float* __restrict__ Av,
    const float* __restrict__ Wq, const float* __restrict__ Wk, const float* __restrict__ Wv,
    const float* __restrict__ bq, const float* __restrict__ bk, const float* __restrict__ bv,
    u16* __restrict__ Qh, u16* __restrict__ Kh, u16* __restrict__ Vh, float csc)
{
  __shared__ __align__(16) u16 At[2*64*64];
  __shared__ __align__(16) u16 Bt[2*128*64];
  const int m0 = blockIdx.x*64, n0 = blockIdx.y*128;
  const int z = blockIdx.z;
  if (z == 0)
    gemm_core<0,true>(Aq, Wq, bq, csc, csc, Qh, At, Bt, m0, n0);
  else if (z == 1)
    gemm_core<0,true>(Ak, Wk, bk, 1.f, 1.f, Kh, At, Bt, m0, n0);
  else
    gemm_core<2,true>(Av, Wv, bv, 1.f, 1.f, Vh, At, Bt, m0, n0);
}

// output projection
__global__ __launch_bounds__(256) void gemm_out_k(
    const u16* __restrict__ A, const float* __restrict__ Bm,
    const float* __restrict__ bias, float* __restrict__ outp)
{
  __shared__ __align__(16) u16 At[2*64*64];
  __shared__ __align__(16) u16 Bt[2*128*64];
  gemm_core<1,false>(A, Bm, bias, 1.f, 1.f, outp, At, Bt, blockIdx.x*64, blockIdx.y*128);
}

// ---------------- flash attention (swapped-QK^T, per-lane softmax) ----------------
// Q pre-scaled by 0.125*log2(e) -> base-2 softmax. 4 waves x 16 q-rows.
// KV loop manually unrolled x2 so the LDS buffer index is a literal (all swizzled
// addresses fold to base+imm). Single-inst exp2, tree reductions, defer-rescale
// (T13), early global loads (T14), setprio around MFMA (T5).
__global__ __launch_bounds__(256) void flash_attn_k(
    const u16* __restrict__ Q, const u16* __restrict__ K, const u16* __restrict__ VT,
    u16* __restrict__ av)
{
  __shared__ __align__(16) u16 Kt[2][64*64];     // [key][d] swizzled
  __shared__ __align__(16) u16 Vt[2][64*64];     // [d][key] swizzled
  __shared__ __align__(16) u16 Pt[4][16*64];     // per-wave [q][k] swizzled

  const int t = threadIdx.x;
  const int w = t >> 6, lane = t & 63, lg = lane >> 4, lr = lane & 15;
  const int tr = t >> 3, tsl = t & 7;
  const int qb = blockIdx.x;       // 0..31
  const int bh = blockIdx.y;       // 0..23
  const u16* Qb = Q  + (size_t)bh*SEQ*DKV;
  const u16* Kb = K  + (size_t)bh*SEQ*DKV;
  const u16* Vb = VT + (size_t)bh*DKV*SEQ;

  const int qrow = qb*64 + w*16 + lr;
  u16x8 qf[2];
  qf[0] = *reinterpret_cast<const u16x8*>(Qb + (size_t)qrow*DKV + lg*8);
  qf[1] = *reinterpret_cast<const u16x8*>(Qb + (size_t)qrow*DKV + 32 + lg*8);

  f32x4 acc[4] = {};   // O^T: acc[fc][j] -> d = fc*16+lg*4+j, q = lr
  float mrun = -1e30f, lrun = 0.f;

  u16x8 ks[2], vs[2];
  auto LOADKV = [&](int kt0) {
    #pragma unroll
    for (int q = 0; q < 2; ++q) {
      int row = q*32 + tr;
      ks[q] = *reinterpret_cast<const u16x8*>(Kb + (size_t)(kt0+row)*DKV + tsl*8);
    }
    #pragma unroll
    for (int q = 0; q < 2; ++q) {
      int d = q*32 + tr;
      vs[q] = *reinterpret_cast<const u16x8*>(Vb + (size_t)d*SEQ + kt0 + tsl*8);
    }
  };

  const int NT = SEQ/64;   // 32
  LOADKV(0);
  {
    #pragma unroll
    for (int q = 0; q < 2; ++q) {
      int row = q*32 + tr;
      *reinterpret_cast<u16x8*>(&Kt[0][row*64 + ((tsl ^ (row & 7))*8)]) = ks[q];
    }
    #pragma unroll
    for (int q = 0; q < 2; ++q) {
      int d = q*32 + tr;
      *reinterpret_cast<u16x8*>(&Vt[0][d*64 + ((tsl ^ (d & 7))*8)]) = vs[q];
    }
  }
  __syncthreads();

  char* Pw = reinterpret_cast<char*>(&Pt[w][0]);

#define TILE(bi, kt)                                                          \
  do {                                                                        \
    if ((kt)+1 < NT) LOADKV(((kt)+1)*64);                                     \
    f32x4 s[4];                                                               \
    __builtin_amdgcn_s_setprio(1);                                            \
    _Pragma("unroll")                                                         \
    for (int fc = 0; fc < 4; ++fc) {                                          \
      f32x4 z = {};                                                           \
      _Pragma("unroll")                                                       \
      for (int kk = 0; kk < 2; ++kk) {                                        \
        int r = fc*16 + lr;                                                   \
        int slot = (lg + 4*kk) ^ (r & 7);                                     \
        u16x8 kf = *reinterpret_cast<const u16x8*>(&Kt[bi][r*64 + slot*8]);   \
        z = mfma16(kf, qf[kk], z);                                            \
      }                                                                       \
      s[fc] = z;                                                              \
    }                                                                         \
    __builtin_amdgcn_s_setprio(0);                                            \
    float a0 = fmaxf(fmaxf(s[0][0], s[0][1]), s[0][2]);                       \
    float a1 = fmaxf(fmaxf(s[0][3], s[1][0]), s[1][1]);                       \
    float a2 = fmaxf(fmaxf(s[1][2], s[1][3]), s[2][0]);                       \
    float a3 = fmaxf(fmaxf(s[2][1], s[2][2]), s[2][3]);                       \
    float a4 = fmaxf(fmaxf(s[3][0], s[3][1]), s[3][2]);                       \
    float pmax = fmaxf(fmaxf(fmaxf(a0, a1), a2),                              \
                       fmaxf(fmaxf(a3, a4), s[3][3]));                        \
    pmax = fmaxf(pmax, __shfl_xor(pmax, 16));                                 \
    pmax = fmaxf(pmax, __shfl_xor(pmax, 32));                                 \
    if (!__all(pmax <= mrun + 8.f)) {                                         \
      float mnew = fmaxf(mrun, pmax);                                         \
      float corr = fexp2(mrun - mnew);                                        \
      mrun = mnew; lrun *= corr;                                              \
      _Pragma("unroll")                                                       \
      for (int fc = 0; fc < 4; ++fc)                                          \
        _Pragma("unroll")                                                     \
        for (int j = 0; j < 4; ++j)                                           \
          acc[fc][j] *= corr;                                                 \
    }                                                                         \
    float p[4][4], rs[4];                                                     \
    _Pragma("unroll")                                                         \
    for (int fc = 0; fc < 4; ++fc) {                                          \
      _Pragma("unroll")                                                       \
      for (int j = 0; j < 4; ++j) p[fc][j] = fexp2(s[fc][j] - mrun);          \
      rs[fc] = (p[fc][0] + p[fc][1]) + (p[fc][2] + p[fc][3]);                 \
    }                                                                         \
    float rsum = (rs[0] + rs[1]) + (rs[2] + rs[3]);                           \
    rsum += __shfl_xor(rsum, 16);                                             \
    rsum += __shfl_xor(rsum, 32);                                             \
    lrun += rsum;                                                             \
    _Pragma("unroll")                                                         \
    for (int fc = 0; fc < 4; ++fc) {                                          \
      u16x4 q4;                                                               \
      _Pragma("unroll")                                                       \
      for (int j = 0; j < 4; ++j) q4[j] = f2bf(p[fc][j]);                     \
      *reinterpret_cast<u16x4*>(                                              \
          Pw + lr*128 + (((fc*4 + lg) ^ ((lr & 7) << 1))*8)) = q4;            \
    }                                                                         \
    asm volatile("s_waitcnt lgkmcnt(0)" ::: "memory");                        \
    __builtin_amdgcn_sched_barrier(0);                                        \
    __builtin_amdgcn_s_setprio(1);                                            \
    _Pragma("unroll")                                                         \
    for (int kk = 0; kk < 2; ++kk) {                                          \
      u16x8 pf = *reinterpret_cast<const u16x8*>(                             \
          Pw + lr*128 + (((kk*8 + lg*2) ^ ((lr & 7) << 1))*8));               \
      _Pragma("unroll")                                                       \
      for (int fc = 0; fc < 4; ++fc) {                                        \
        int rv = fc*16 + lr;                                                  \
        int slotv = (lg + 4*kk) ^ (rv & 7);                                   \
        u16x8 vf = *reinterpret_cast<const u16x8*>(&Vt[bi][rv*64 + slotv*8]); \
        acc[fc] = mfma16(vf, pf, acc[fc]);                                    \
      }                                                                       \
    }                                                                         \
    __builtin_amdgcn_s_setprio(0);                                            \
    if ((kt)+1 < NT) {                                                        \
      _Pragma("unroll")                                                       \
      for (int q = 0; q < 2; ++q) {                                           \
        int row = q*32 + tr;                                                  \
        *reinterpret_cast<u16x8*>(                                            \
            &Kt[(bi)^1][row*64 + ((tsl ^ (row & 7))*8)]) = ks[q];             \
      }                                                                       \
      _Pragma("unroll")                                                       \
      for (int q = 0; q < 2; ++q) {                                           \
        int d = q*32 + tr;                                                    \
        *reinterpret_cast<u16x8*>(                                            \
            &Vt[(bi)^1][d*64 + ((tsl ^ (d & 7))*8)]) = vs[q];                 \
      }                                                                       \
    }                                                                         \
    __syncthreads();                                                          \
  } while (0)

  for (int kt = 0; kt < NT; kt += 2) {
    TILE(0, kt);
    TILE(1, kt+1);
  }
#undef TILE

  // epilogue: lane owns q=qrow; d contiguous -> 8B stores
  const int b = bh / HEADS, h = bh % HEADS;
  const float inv = 1.0f / lrun;
  #pragma unroll
  for (int fc = 0; fc < 4; ++fc) {
    u16x4 o4;
    #pragma unroll
    for (int j = 0; j < 4; ++j) o4[j] = f2bf(acc[fc][j] * inv);
    *reinterpret_cast<u16x4*>(
        av + ((size_t)(b*SEQ + qrow))*EMB + h*64 + fc*16 + lg*4) = o4;
  }
}

// ---------------- launcher: 3 kernels ----------------
extern "C" void kernel_launch(void* const* d_in, const int* in_sizes, int n_in,
                              void* d_out, int out_size, void* d_ws, size_t ws_size,
                              hipStream_t stream) {
  const float* xq_f = (const float*)d_in[0];
  const float* xk_f = (const float*)d_in[1];
  const float* xv_f = (const float*)d_in[2];
  const float* Wq = (const float*)d_in[3];
  const float* bq = (const float*)d_in[4];
  const float* Wk = (const float*)d_in[5];
  const float* bk = (const float*)d_in[6];
  const float* Wv = (const float*)d_in[7];
  const float* bv = (const float*)d_in[8];
  const float* Wo = (const float*)d_in[9];
  const float* bo = (const float*)d_in[10];

  u16* Qh = (u16*)d_ws;                       // [B][H][S][DKV] bf16
  u16* Kh = Qh + (size_t)NTOK*EMB;
  u16* Vh = Kh + (size_t)NTOK*EMB;            // [B][H][DKV][SEQ] bf16 (V^T)
  u16* Xb = Vh + (size_t)NTOK*EMB;            // attention output bf16

  const float csc = 0.125f * 1.4426950408889634f;  // score scale, folded into Q proj

  qkv_k<<<dim3(NTOK/64, EMB/128, 3), dim3(256), 0, stream>>>(
      xq_f, xk_f, xv_f, Wq, Wk, Wv, bq, bk, bv, Qh, Kh, Vh, csc);

  flash_attn_k<<<dim3(SEQ/64, BATCH*HEADS), dim3(256), 0, stream>>>(Qh, Kh, Vh, Xb);

  gemm_out_k<<<dim3(NTOK/64, EMB/128), dim3(256), 0, stream>>>(Xb, Wo, bo, (float*)d_out);
}